// Round 10
// baseline (233.684 us; speedup 1.0000x reference)
//
#include <hip/hip_runtime.h>
#include <hip/hip_bf16.h>

#define ENC 2048
#define ADIM 512
#define DEC 512
#define NBATCH 128
#define NL 196
#define MTOT (NBATCH * NL)   // 25088
#define NKT 32               // K-steps of 64

typedef __attribute__((ext_vector_type(8))) short short8;
typedef __attribute__((ext_vector_type(4))) float f32x4;
typedef __attribute__((ext_vector_type(4))) unsigned int u32x4;

__device__ __forceinline__ unsigned short f2bf(float f) {
    __hip_bfloat16 h = __float2bfloat16(f);
    union { __hip_bfloat16 h; unsigned short u; } cv; cv.h = h; return cv.u;
}
__device__ __forceinline__ unsigned int f2bf2(float lo, float hi) {
    __hip_bfloat162 h = __float22bfloat162_rn(float2{lo, hi});
    union { __hip_bfloat162 h; unsigned int u; } cv; cv.h = h; return cv.u;
}

// ---------------- kernel 1: w_ah = hidden @ W_w + W_b  [128 x 512] ----------------
__global__ void wah_kernel(const float* __restrict__ hidden, const float* __restrict__ Ww,
                           const float* __restrict__ Wb, float* __restrict__ wah) {
    __shared__ __align__(16) float hs[DEC];
    const int b = blockIdx.x, a = threadIdx.x;   // block 512 threads
    hs[a] = hidden[b * DEC + a];
    __syncthreads();
    float acc = Wb[a];
    #pragma unroll 4
    for (int d = 0; d < DEC; d += 4) {
        f32x4 h = *(const f32x4*)&hs[d];
        acc += h.x * Ww[(d    ) * ADIM + a];
        acc += h.y * Ww[(d + 1) * ADIM + a];
        acc += h.z * Ww[(d + 2) * ADIM + a];
        acc += h.w * Ww[(d + 3) * ADIM + a];
    }
    wah[b * ADIM + a] = acc;
}

// ---------------- kernel 2: U_w [K=2048][N=512] fp32 -> uwTf bf16 FRAGMENT layout ----
// Fragment (nf 0..31, kf 0..63): lane l, elem j holds U_w[kf*32 + (l>>4)*8 + j][nf*16 + (l&15)].
// Flat: uwTf[((nf*64 + kf)*64 + lane)*8 + j]. Each fragment = 1KB contiguous ->
// the GEMM's B loads are 64-lane x 16B coalesced single instructions, L2-resident.
__global__ void transpose_uw_frag(const float* __restrict__ Uw, unsigned short* __restrict__ uwTf) {
    __shared__ float t[32][33];
    const int k0 = blockIdx.x * 32, n0 = blockIdx.y * 32;
    const int tx = threadIdx.x, ty = threadIdx.y;   // 32 x 8
    #pragma unroll
    for (int i = 0; i < 4; ++i)
        t[ty + 8 * i][tx] = Uw[(size_t)(k0 + ty + 8 * i) * ADIM + n0 + tx];
    __syncthreads();
    const int kf  = k0 >> 5;
    const int nf  = (n0 >> 4) + (tx >> 4);
    const int l15 = tx & 15;
    const int ldr = ty >> 1, j0 = (ty & 1) * 4;
    const int kl0 = ty * 4;                    // == ldr*8 + j0
    unsigned int lo = f2bf2(t[kl0 + 0][tx], t[kl0 + 1][tx]);
    unsigned int hi = f2bf2(t[kl0 + 2][tx], t[kl0 + 3][tx]);
    unsigned int* dst = (unsigned int*)(uwTf + ((size_t)((nf * 64 + kf) * 64 + ldr * 16 + l15)) * 8 + j0);
    dst[0] = lo;
    dst[1] = hi;
}

// ---------------- kernel 3: fused GEMM + tanh + A_w-dot -> score partials ----------------
// 128x128 tile, BK=64, 4 waves 2x2 (wave tile 64x64), NO cvt pre-pass:
//  A: fp32 feat -> regs (issued BEFORE compute, T14) -> cvt bf16 -> ds_write AFTER
//     compute into the OTHER named buffer (alias-safe) -> __syncthreads drains
//     loads that already had the whole compute phase to land.
//  B: NO LDS - direct coalesced 1KB fragment loads from uwTf (L2-resident 2MB),
//     issued FIRST each step so compiler's pre-MFMA wait is vmcnt(8), leaving
//     the A loads in flight.
// LDS per step: 16KB write + 32KB frag reads (swizzled, 0-conflict, R9-proven).
__global__ __launch_bounds__(256, 3) void gemm_score(
    const float* __restrict__ feat, const unsigned short* __restrict__ uwTf,
    const float* __restrict__ Ub, const float* __restrict__ wahb,
    const float* __restrict__ Aw, float* __restrict__ part)
{
    __shared__ __align__(16) unsigned char Ab0[16384];   // [128][64] bf16 swizzled
    __shared__ __align__(16) unsigned char Ab1[16384];

    const int tid  = threadIdx.x;
    const int lane = tid & 63;
    const int w    = tid >> 6;
    const int wr   = w >> 1, wc = w & 1;
    const int l15  = lane & 15, ldr = lane >> 4;

    // bijective XCD swizzle: 784 blocks = 8 XCD chunks of 98 (nbk fastest -> A-panel shared in L2)
    const int bid  = blockIdx.x;
    const int work = (bid & 7) * 98 + (bid >> 3);
    const int mb   = work >> 2;    // 0..195
    const int nbk  = work & 3;     // 0..3

    // ---- A staging: thread -> row r_=tid>>1, k-half h_ (32 floats = 8 f32x4) ----
    const int r_ = tid >> 1, h_ = tid & 1;
    const float* aSrc = feat + (size_t)(mb * 128 + r_) * ENC + h_ * 32;
    int wA[4];
    #pragma unroll
    for (int j = 0; j < 4; ++j)
        wA[j] = r_ * 128 + (((h_ * 4 + j) ^ (r_ & 7)) << 4);

    // ---- B fragment base (in shorts): frag (f,ks) at kt -> + f*32768 + (kt*2+ks)*512 ----
    const unsigned short* bBase = uwTf + ((size_t)(nbk * 8 + wc * 4) * 4096 + (size_t)lane) * 8;

    // ---- A fragment read offsets (swizzled, 0-conflict) ----
    int abyte[4][2];
    #pragma unroll
    for (int f = 0; f < 4; ++f) {
        const int ra = wr * 64 + f * 16 + l15;
        #pragma unroll
        for (int ks = 0; ks < 2; ++ks)
            abyte[f][ks] = ra * 128 + (((ks * 4 + ldr) ^ (ra & 7)) << 4);
    }

    f32x4 acc[4][4];
    #pragma unroll
    for (int i = 0; i < 4; ++i)
        #pragma unroll
        for (int j = 0; j < 4; ++j)
            acc[i][j] = (f32x4){0.f, 0.f, 0.f, 0.f};

    f32x4 ar[8];     // staged A fp32 (single set: consumed before re-issue)
    short8 be[8];    // B frags (f*2+ks)

#define ISSUE_B(KT) {                                                         \
    _Pragma("unroll")                                                         \
    for (int f = 0; f < 4; ++f)                                               \
        _Pragma("unroll")                                                     \
        for (int ks = 0; ks < 2; ++ks)                                        \
            be[f * 2 + ks] = *(const short8*)(bBase + f * 32768 + ((KT) * 2 + ks) * 512); \
    __builtin_amdgcn_sched_barrier(0);                                        \
}
#define LOAD_A(KT) {                                                          \
    const f32x4* p = (const f32x4*)(aSrc + (size_t)(KT) * 64);                \
    _Pragma("unroll")                                                         \
    for (int j = 0; j < 8; ++j) ar[j] = p[j];                                 \
    __builtin_amdgcn_sched_barrier(0);                                        \
}
#define CVTW(AB) {                                                            \
    _Pragma("unroll")                                                         \
    for (int j = 0; j < 4; ++j) {                                             \
        u32x4 wv;                                                             \
        wv.x = f2bf2(ar[2*j].x,   ar[2*j].y);                                 \
        wv.y = f2bf2(ar[2*j].z,   ar[2*j].w);                                 \
        wv.z = f2bf2(ar[2*j+1].x, ar[2*j+1].y);                               \
        wv.w = f2bf2(ar[2*j+1].z, ar[2*j+1].w);                               \
        *(u32x4*)((AB) + wA[j]) = wv;                                         \
    }                                                                         \
}
#define COMPUTE(AB) {                                                         \
    __builtin_amdgcn_s_setprio(1);                                            \
    _Pragma("unroll")                                                         \
    for (int ks = 0; ks < 2; ++ks) {                                          \
        short8 af[4];                                                         \
        _Pragma("unroll")                                                     \
        for (int f = 0; f < 4; ++f)                                           \
            af[f] = *(const short8*)((AB) + abyte[f][ks]);                    \
        _Pragma("unroll")                                                     \
        for (int fm = 0; fm < 4; ++fm)                                        \
            _Pragma("unroll")                                                 \
            for (int fn = 0; fn < 4; ++fn)                                    \
                acc[fm][fn] = __builtin_amdgcn_mfma_f32_16x16x32_bf16(        \
                    af[fm], be[fn * 2 + ks], acc[fm][fn], 0, 0, 0);           \
    }                                                                         \
    __builtin_amdgcn_s_setprio(0);                                            \
    __builtin_amdgcn_sched_barrier(0);                                        \
}

    // prologue: stage A(0) into Ab0
    LOAD_A(0);
    CVTW(Ab0);
    __syncthreads();

    #pragma unroll 1
    for (int kt = 0; kt < NKT; kt += 2) {
        const int k1 = kt + 1;
        const int k2 = (kt + 2 < NKT) ? kt + 2 : NKT - 1;
        // even phase: B(t) first (oldest -> vmcnt(8) pre-MFMA), A(t+1) in flight under compute
        ISSUE_B(kt);
        LOAD_A(k1);
        COMPUTE(Ab0);
        CVTW(Ab1);
        __syncthreads();
        // odd phase
        ISSUE_B(k1);
        LOAD_A(k2);
        COMPUTE(Ab1);
        CVTW(Ab0);
        __syncthreads();
    }
#undef ISSUE_B
#undef LOAD_A
#undef CVTW
#undef COMPUTE

    // epilogue: score partial = sum_c Aw[c] * tanh(acc + Ub[c] + wah[b][c])
    float ub4[4], aw4[4]; int cidx[4];
    #pragma unroll
    for (int f = 0; f < 4; ++f) {
        const int c = nbk * 128 + wc * 64 + f * 16 + l15;
        cidx[f] = c; ub4[f] = Ub[c]; aw4[f] = Aw[c];
    }
    #pragma unroll
    for (int fm = 0; fm < 4; ++fm) {
        #pragma unroll
        for (int r = 0; r < 4; ++r) {
            const int m = mb * 128 + wr * 64 + fm * 16 + ldr * 4 + r;
            const int b = m / NL;
            const float* wrow = wahb + b * ADIM;
            float s = 0.f;
            #pragma unroll
            for (int f = 0; f < 4; ++f)
                s += aw4[f] * tanhf(acc[fm][f][r] + ub4[f] + wrow[cidx[f]]);
            s += __shfl_xor(s, 1);
            s += __shfl_xor(s, 2);
            s += __shfl_xor(s, 4);
            s += __shfl_xor(s, 8);
            if (l15 == 0) part[(nbk * 2 + wc) * MTOT + m] = s;
        }
    }
}

// ---------------- kernel 4: reduce partials + softmax over L -> alpha ----------------
__global__ void softmax_kernel(const float* __restrict__ part, const float* __restrict__ Ab,
                               float* __restrict__ alpha) {
    const int b = blockIdx.x, t = threadIdx.x;   // 256 threads
    float sv = 0.f;
    if (t < NL) {
        sv = Ab[0];
        #pragma unroll
        for (int p = 0; p < 8; ++p) sv += part[p * MTOT + b * NL + t];
    }
    float v = (t < NL) ? sv : -3.4e38f;
    #pragma unroll
    for (int o = 32; o >= 1; o >>= 1) v = fmaxf(v, __shfl_xor(v, o));
    __shared__ float rm[4], rs[4];
    if ((t & 63) == 0) rm[t >> 6] = v;
    __syncthreads();
    const float bm = fmaxf(fmaxf(rm[0], rm[1]), fmaxf(rm[2], rm[3]));
    const float e = (t < NL) ? expf(sv - bm) : 0.f;
    float s = e;
    #pragma unroll
    for (int o = 32; o >= 1; o >>= 1) s += __shfl_xor(s, o);
    if ((t & 63) == 0) rs[t >> 6] = s;
    __syncthreads();
    const float bs = rs[0] + rs[1] + rs[2] + rs[3];
    if (t < NL) alpha[b * NL + t] = e / bs;
}

// ---------------- kernel 5: context[b][e] = sum_l alpha[b][l] * feat[b][l][e] ----------------
__global__ void context_kernel(const float* __restrict__ feat, const float* __restrict__ alpha,
                               float* __restrict__ ctx) {
    __shared__ float al[NL];
    const int b = blockIdx.x, chunk = blockIdx.y, t = threadIdx.x;  // 128 threads
    for (int i = t; i < NL; i += 128) al[i] = alpha[b * NL + i];
    __syncthreads();
    const int e0 = chunk * 512 + t * 4;
    const float* fp = feat + (size_t)b * NL * ENC + e0;
    f32x4 acc0 = (f32x4){0.f, 0.f, 0.f, 0.f};
    f32x4 acc1 = (f32x4){0.f, 0.f, 0.f, 0.f};
    #pragma unroll 2
    for (int l = 0; l < NL; l += 2) {
        f32x4 f0 = *(const f32x4*)(fp + (size_t)l * ENC);
        f32x4 f1 = *(const f32x4*)(fp + (size_t)(l + 1) * ENC);
        acc0 += al[l] * f0;
        acc1 += al[l + 1] * f1;
    }
    f32x4 rsum = acc0 + acc1;
    *(f32x4*)(ctx + (size_t)b * ENC + e0) = rsum;
}

extern "C" void kernel_launch(void* const* d_in, const int* in_sizes, int n_in,
                              void* d_out, int out_size, void* d_ws, size_t ws_size,
                              hipStream_t stream) {
    const float* feat   = (const float*)d_in[0];
    const float* hidden = (const float*)d_in[1];
    const float* Uw     = (const float*)d_in[2];
    const float* Ub     = (const float*)d_in[3];
    const float* Ww     = (const float*)d_in[4];
    const float* Wb     = (const float*)d_in[5];
    const float* Aw     = (const float*)d_in[6];
    const float* Ab     = (const float*)d_in[7];

    float* out   = (float*)d_out;
    float* alpha = out;              // [128*196]
    float* ctx   = out + MTOT;       // [128*2048]

    char* ws = (char*)d_ws;
    float*          wahb  = (float*)ws;                          // 256 KB
    unsigned short* uwTf  = (unsigned short*)(ws + 262144);      // 2 MB (fragment layout)
    float*          partb = (float*)(ws + 262144 + 2097152);     // 8*25088*4 = 784 KB

    wah_kernel<<<dim3(128), dim3(512), 0, stream>>>(hidden, Ww, Wb, wahb);
    transpose_uw_frag<<<dim3(64, 16), dim3(32, 8), 0, stream>>>(Uw, uwTf);
    gemm_score<<<dim3(784), dim3(256), 0, stream>>>(feat, uwTf, Ub, wahb, Aw, partb);
    softmax_kernel<<<dim3(128), dim3(256), 0, stream>>>(partb, Ab, alpha);
    context_kernel<<<dim3(128, 4), dim3(128), 0, stream>>>(feat, alpha, ctx);
}